// Round 1
// baseline (7774.570 us; speedup 1.0000x reference)
//
#include <hip/hip_runtime.h>

#define SEQ 2048
#define DH  64
#define NH  16
#define NB  4
#define TQ  4
#define NT  256

__global__ __launch_bounds__(NT) void attn_fwd(
    const float* __restrict__ Q, const float* __restrict__ K,
    const float* __restrict__ V, const int* __restrict__ pad,
    float* __restrict__ out_res, float* __restrict__ out_w)
{
    __shared__ __attribute__((aligned(16))) float s_q[TQ][DH];   // 1 KB
    __shared__ float s_s[TQ][SEQ];                               // 32 KB: scores -> weights
    __shared__ float s_red[2][TQ][4];
    __shared__ float s_o[TQ][4][DH];                             // 4 KB

    const int t     = threadIdx.x;
    const int bid   = blockIdx.x;
    const int qtile = bid & (SEQ / TQ - 1);      // 512 q-tiles per head
    const int h     = (bid >> 9) & (NH - 1);
    const int b     = bid >> 13;
    const int q0    = qtile * TQ;

    const size_t head_off = ((size_t)(b * NH + h)) * SEQ * DH;
    const float* Kh   = K + head_off;
    const float* Vh   = V + head_off;
    const int*   padb = pad + b * SEQ;

    // ---- load Q tile (4 rows x 64) ----
    {
        int r = t >> 6, d = t & 63;
        s_q[r][d] = Q[head_off + (size_t)(q0 + r) * DH + d];
    }
    __syncthreads();

    // ---- scores: each thread handles k = t + i*256, all 4 q-rows ----
    float sc[8][TQ];
    float lm[TQ];
#pragma unroll
    for (int r = 0; r < TQ; ++r) lm[r] = -3.0e38f;

#pragma unroll
    for (int i = 0; i < 8; ++i) {
        const int k = t + i * NT;
        const int pd = padb[k];
        const float4* krow = (const float4*)(Kh + (size_t)k * DH);
        float acc[TQ] = {0.f, 0.f, 0.f, 0.f};
#pragma unroll
        for (int j = 0; j < 16; ++j) {
            float4 kv = krow[j];
#pragma unroll
            for (int r = 0; r < TQ; ++r) {
                float4 qv = ((const float4*)s_q[r])[j];
                acc[r] += kv.x * qv.x + kv.y * qv.y + kv.z * qv.z + kv.w * qv.w;
            }
        }
#pragma unroll
        for (int r = 0; r < TQ; ++r) {
            float s = acc[r] * 0.125f;  // 1/sqrt(64)
            // masked iff (k > q) XOR (pad == 1)   [combined == 1 exactly]
            const bool masked = ((k > q0 + r) != (pd == 1));
            if (masked) s = -1.0e9f;
            sc[i][r] = s;
            lm[r] = fmaxf(lm[r], s);
        }
    }

    // ---- row max: wave butterfly then cross-wave via LDS ----
    const int wave = t >> 6;
#pragma unroll
    for (int r = 0; r < TQ; ++r) {
        float v = lm[r];
        for (int off = 32; off > 0; off >>= 1)
            v = fmaxf(v, __shfl_xor(v, off, 64));
        lm[r] = v;
    }
    if ((t & 63) == 0) {
#pragma unroll
        for (int r = 0; r < TQ; ++r) s_red[0][r][wave] = lm[r];
    }
    __syncthreads();

    float m[TQ], lsum[TQ];
#pragma unroll
    for (int r = 0; r < TQ; ++r) {
        m[r] = fmaxf(fmaxf(s_red[0][r][0], s_red[0][r][1]),
                     fmaxf(s_red[0][r][2], s_red[0][r][3]));
        lsum[r] = 0.f;
    }

    // ---- exp + row sum ----
#pragma unroll
    for (int i = 0; i < 8; ++i) {
#pragma unroll
        for (int r = 0; r < TQ; ++r) {
            float e = __expf(sc[i][r] - m[r]);
            sc[i][r] = e;
            lsum[r] += e;
        }
    }
#pragma unroll
    for (int r = 0; r < TQ; ++r) {
        float v = lsum[r];
        for (int off = 32; off > 0; off >>= 1)
            v += __shfl_xor(v, off, 64);
        lsum[r] = v;
    }
    if ((t & 63) == 0) {
#pragma unroll
        for (int r = 0; r < TQ; ++r) s_red[1][r][wave] = lsum[r];
    }
    __syncthreads();

    float inv[TQ];
#pragma unroll
    for (int r = 0; r < TQ; ++r)
        inv[r] = 1.0f / (s_red[1][r][0] + s_red[1][r][1] +
                         s_red[1][r][2] + s_red[1][r][3]);

    // ---- normalize: stash in LDS + coalesced global write ----
    const size_t wbase = (size_t)bid * TQ * SEQ;
#pragma unroll
    for (int i = 0; i < 8; ++i) {
        const int k = t + i * NT;
#pragma unroll
        for (int r = 0; r < TQ; ++r) {
            float w = sc[i][r] * inv[r];
            s_s[r][k] = w;
            out_w[wbase + (size_t)r * SEQ + k] = w;
        }
    }
    __syncthreads();

    // ---- PV: thread (c,d) covers k in [c*512,(c+1)*512), column d ----
    {
        const int d = t & 63;
        const int c = t >> 6;
        float oacc[TQ] = {0.f, 0.f, 0.f, 0.f};
        const int k0 = c * (SEQ / 4);
#pragma unroll 4
        for (int kk = 0; kk < SEQ / 4; ++kk) {
            const int k = k0 + kk;
            float vv = Vh[(size_t)k * DH + d];
#pragma unroll
            for (int r = 0; r < TQ; ++r) oacc[r] += s_s[r][k] * vv;
        }
#pragma unroll
        for (int r = 0; r < TQ; ++r) s_o[r][c][d] = oacc[r];
    }
    __syncthreads();
    {
        const int d = t & 63;
        const int r = t >> 6;
        float o = s_o[r][0][d] + s_o[r][1][d] + s_o[r][2][d] + s_o[r][3][d];
        out_res[(size_t)(bid * TQ + r) * DH + d] = o;
    }
}

extern "C" void kernel_launch(void* const* d_in, const int* in_sizes, int n_in,
                              void* d_out, int out_size, void* d_ws, size_t ws_size,
                              hipStream_t stream) {
    const float* Q   = (const float*)d_in[0];
    const float* K   = (const float*)d_in[1];
    const float* V   = (const float*)d_in[2];
    const int*   pad = (const int*)d_in[3];
    float* out_res = (float*)d_out;
    float* out_w   = out_res + (size_t)NB * NH * SEQ * DH;

    dim3 grid(NB * NH * (SEQ / TQ));   // 32768 blocks
    attn_fwd<<<grid, NT, 0, stream>>>(Q, K, V, pad, out_res, out_w);
}